// Round 15
// baseline (123.637 us; speedup 1.0000x reference)
//
#include <hip/hip_runtime.h>

#define NV  778
#define NK  146    // coef: 1 (template) + 10 (beta) + 135 (pose_feature)
#define NKQ 152    // Gq rows padded to multiple of 8 (rows 146..151 zero)
#define GC  8      // batches per kC block (512 blocks = 2/CU)
#define VCH 98     // v-chunk per Gq fold block (8 chunks cover 778)
#define VCHP 100   // padded LDS stride (mult of 4 for b128; breaks bank alias)
#define NCH 8      // chunk count

// Finger vertex ids
#define FV0 734
#define FV1 333
#define FV2 443
#define FV3 555
#define FV4 678

__device__ __forceinline__ const float* d_row(int k,
                                              const float* vt,
                                              const float* sd,
                                              const float* pd) {
    return (k == 0) ? vt : (k <= 10 ? sd + (size_t)(k-1)*(NV*3)
                                    : pd + (size_t)(k-11)*(NV*3));
}

// ---------------------------------------------------------------------------
// k_fold roles (blockIdx):
//   [0,1168)         Gq partials, LDS-lean: jreg/wts transposed in LDS
//                    (float4 over v), D-row via block-uniform scalar loads.
//   [1168,1300)      SJ[480]/JT[48]
//   [1300,1364)      WJ[256]
//   [1364,1364+npb)  pose PCA + Rodrigues -> coefG/R0G
//   1364+npb         Dfing/Wfing gathers
// ---------------------------------------------------------------------------
__launch_bounds__(256)
__global__ void k_fold(const float* __restrict__ vt,
                       const float* __restrict__ sd,
                       const float* __restrict__ pd,
                       const float* __restrict__ jreg,
                       const float* __restrict__ wts,
                       const float* __restrict__ beta,
                       const float* __restrict__ theta,
                       const float* __restrict__ hm,
                       const float* __restrict__ hc,
                       float* __restrict__ SJ, float* __restrict__ JT,
                       float* __restrict__ WJ, float* __restrict__ Gqp,
                       float* __restrict__ coefG, float* __restrict__ R0G,
                       float* __restrict__ Dfing, float* __restrict__ Wfing,
                       int Btot, int npb)
{
    const int o = blockIdx.x;
    const int tid = threadIdx.x;

    __shared__ float p_hc[2025];
    __shared__ float p_th[8][48];
    __shared__ float p_pose[8][45];
    __shared__ __align__(16) float l_jT[16*VCHP];
    __shared__ __align__(16) float l_wT[16*VCHP];

    if (o < 1168) {
        const int k = o >> 3, chunk = o & 7;
        const float* Drow = d_row(k, vt, sd, pd);
        const int v0 = chunk * VCH;
        const int v1 = (v0 + VCH < NV) ? (v0 + VCH) : NV;
        const int n = v1 - v0;
        // stage transposed: l_jT[c][v], l_wT[c][v]
        for (int i = tid; i < n*16; i += 256) {
            int v = i >> 4, c = i & 15;
            l_jT[c*VCHP + v] = jreg[(size_t)(v0+v)*16 + c];
            l_wT[c*VCHP + v] = wts [(size_t)(v0+v)*16 + c];
        }
        __syncthreads();
        const int J = tid >> 4, j = tid & 15;
        const float* jb = l_jT + J*VCHP;
        const float* wb = l_wT + j*VCHP;
        const float* dp = Drow + (size_t)v0*3;   // block-uniform -> scalar loads
        float a0 = 0.f, a1 = 0.f, a2 = 0.f;
        const int n4 = n & ~3;
        for (int v = 0; v < n4; v += 4) {
            float4 jv = *(const float4*)(jb + v);
            float4 wv = *(const float4*)(wb + v);
            const float* d4 = dp + v*3;          // uniform
            float p0 = jv.x*wv.x, p1 = jv.y*wv.y, p2 = jv.z*wv.z, p3 = jv.w*wv.w;
            a0 += d4[0]*p0;  a1 += d4[1]*p0;  a2 += d4[2]*p0;
            a0 += d4[3]*p1;  a1 += d4[4]*p1;  a2 += d4[5]*p1;
            a0 += d4[6]*p2;  a1 += d4[7]*p2;  a2 += d4[8]*p2;
            a0 += d4[9]*p3;  a1 += d4[10]*p3; a2 += d4[11]*p3;
        }
        for (int v = n4; v < n; ++v) {
            float pv = jb[v] * wb[v];
            const float* dv = dp + v*3;
            a0 += dv[0]*pv; a1 += dv[1]*pv; a2 += dv[2]*pv;
        }
        float* gp = Gqp + (((size_t)chunk*NK + k)*256 + tid)*3;
        gp[0] = a0; gp[1] = a1; gp[2] = a2;
    } else if (o < 1300) {
        const int idx = (o - 1168)*4 + (tid >> 6);   // 0..527
        const int t = tid & 63;
        const float* src; int jc;
        if (idx < 480) { int k = idx / 48; jc = idx % 48; src = sd + (size_t)k*(NV*3); }
        else           { jc = idx - 480;              src = vt; }
        int j = jc / 3, c = jc % 3;
        float acc = 0.f;
        for (int v = t; v < NV; v += 64)
            acc += src[3*v + c] * jreg[v*16 + j];
        for (int off = 32; off; off >>= 1) acc += __shfl_down(acc, off, 64);
        if (t == 0) { if (idx < 480) SJ[idx] = acc; else JT[jc] = acc; }
    } else if (o < 1364) {
        const int cidx = (o - 1300)*4 + (tid >> 6);  // 0..255
        const int t = tid & 63;
        const int J = cidx >> 4, j = cidx & 15;
        float acc = 0.f;
        for (int v = t; v < NV; v += 64)
            acc += jreg[v*16 + J] * wts[v*16 + j];
        for (int off = 32; off; off >>= 1) acc += __shfl_down(acc, off, 64);
        if (t == 0) WJ[cidx] = acc;
    } else if (o < 1364 + npb) {
        const int b0 = (o - 1364) * 8;
        for (int i = tid; i < 2025; i += 256) p_hc[i] = hc[i];
        for (int i = tid; i < 8*48; i += 256) {
            int g = i / 48, t = i % 48, b = b0 + g;
            p_th[g][t] = (b < Btot) ? theta[(size_t)b*48 + t] : 0.f;
        }
        __syncthreads();
        for (int i = tid; i < 8*45; i += 256) {
            int g = i / 45, t = i % 45;
            float acc = hm[t];
            #pragma unroll 9
            for (int k = 0; k < 45; ++k) acc += p_th[g][3+k] * p_hc[k*45 + t];
            p_pose[g][t] = acc;
        }
        __syncthreads();
        if (tid < 128) {
            int g = tid >> 4, jt = tid & 15;
            int b = b0 + g;
            if (b < Btot) {
                float rx, ry, rz;
                if (jt == 0) { rx = p_th[g][0]; ry = p_th[g][1]; rz = p_th[g][2]; }
                else { rx = p_pose[g][3*(jt-1)+0]; ry = p_pose[g][3*(jt-1)+1]; rz = p_pose[g][3*(jt-1)+2]; }
                float ex = rx + 1e-8f, ey = ry + 1e-8f, ez = rz + 1e-8f;
                float angle = sqrtf(ex*ex + ey*ey + ez*ez);
                float inv = 1.f / angle;
                float x = rx*inv, y = ry*inv, z = rz*inv;
                float s  = sinf(angle);
                float c1 = 1.f - cosf(angle);
                float R[9];
                R[0] = 1.f + c1*(-(z*z + y*y));
                R[1] = -s*z + c1*(x*y);
                R[2] =  s*y + c1*(x*z);
                R[3] =  s*z + c1*(x*y);
                R[4] = 1.f + c1*(-(x*x + z*z));
                R[5] = -s*x + c1*(y*z);
                R[6] = -s*y + c1*(x*z);
                R[7] =  s*x + c1*(y*z);
                R[8] = 1.f + c1*(-(x*x + y*y));
                float* cg = coefG + (size_t)b*152;
                if (jt == 0) {
                    #pragma unroll
                    for (int i = 0; i < 9; ++i) R0G[(size_t)b*9 + i] = R[i];
                    cg[0] = 1.f;
                    #pragma unroll
                    for (int k = 0; k < 10; ++k) cg[1+k] = beta[(size_t)b*10 + k];
                    #pragma unroll
                    for (int k = 146; k < 152; ++k) cg[k] = 0.f;
                } else {
                    #pragma unroll
                    for (int i = 0; i < 9; ++i)
                        cg[11 + (jt-1)*9 + i] = R[i] - ((i % 4 == 0) ? 1.f : 0.f);
                }
            }
        }
    } else {
        const int fv[5] = {FV0, FV1, FV2, FV3, FV4};
        for (int e = tid; e < NK*15; e += 256) {
            int k = e / 15, r = e % 15, f = r / 3, q = r % 3;
            Dfing[e] = d_row(k, vt, sd, pd)[3*fv[f] + q];
        }
        if (tid < 80) {
            int f = tid >> 4, j = tid & 15;
            Wfing[tid] = wts[fv[f]*16 + j];
        }
    }
}

// ---------------------------------------------------------------------------
// k_red: Gq[k][c][q] = sum_ch Gqp[ch][k][c][q]; zeros for padded rows.
// ---------------------------------------------------------------------------
__launch_bounds__(256)
__global__ void k_red(const float* __restrict__ Gqp, float* __restrict__ Gq)
{
    const int k = blockIdx.x;      // 0..NKQ-1
    const int c = threadIdx.x;     // 0..255
    float a0 = 0.f, a1 = 0.f, a2 = 0.f;
    if (k < NK) {
        #pragma unroll
        for (int ch = 0; ch < NCH; ++ch) {
            const float* gp = Gqp + (((size_t)ch*NK + k)*256 + c)*3;
            a0 += gp[0]; a1 += gp[1]; a2 += gp[2];
        }
    }
    float* g = Gq + ((size_t)k*256 + c)*3;
    g[0] = a0; g[1] = a1; g[2] = a2;
}

// ---------------------------------------------------------------------------
// kC: unchanged from R14 (GC=8, 512 blocks, double-buffered phase 2).
// ---------------------------------------------------------------------------
__launch_bounds__(256)
__global__ void kC(const float* __restrict__ SJ,
                   const float* __restrict__ JT,
                   const float* __restrict__ WJ,
                   const float* __restrict__ Gq,
                   const float* __restrict__ coefG,
                   const float* __restrict__ R0G,
                   const float* __restrict__ Dfing,
                   const float* __restrict__ Wfing,
                   float* __restrict__ out,
                   int Btot)
{
    const int tid = threadIdx.x;
    const int w = tid >> 6, t = tid & 63;
    const int b0 = blockIdx.x * GC;

    __shared__ float s_SJ[480];
    __shared__ float s_JT[48];
    __shared__ float s_WJ[256];
    __shared__ __align__(16) float s_coef[GC][152];
    __shared__ float s_R0[GC][9];
    __shared__ float s_A[GC][192];
    __shared__ float s_J[GC][48];
    __shared__ float s_vpf[GC][16];
    __shared__ float s_fred[GC][15][2];

    float cur0[8], cur1[8], cur2[8];
    #pragma unroll
    for (int kk = 0; kk < 8; ++kk) {
        const float* gq = Gq + ((size_t)kk*256 + tid)*3;
        cur0[kk] = gq[0]; cur1[kk] = gq[1]; cur2[kk] = gq[2];
    }

    for (int i = tid; i < 480; i += 256) s_SJ[i] = SJ[i];
    if (tid < 48) s_JT[tid] = JT[tid];
    s_WJ[tid] = WJ[tid];
    for (int i = tid; i < GC*152; i += 256) {
        int g = i / 152, k = i % 152, b = b0 + g;
        s_coef[g][k] = (b < Btot) ? coefG[(size_t)b*152 + k] : 0.f;
    }
    if (tid < GC*9) {
        int g = tid / 9, i = tid % 9, b = b0 + g;
        s_R0[g][i] = (b < Btot) ? R0G[(size_t)b*9 + i] : 0.f;
    }
    __syncthreads();

    #pragma unroll
    for (int pp = 0; pp < 2; ++pp) {
        const int g = pp*4 + w;
        const int b = b0 + g;
        if (b < Btot) {
            if (t < 48) {
                float acc = s_JT[t];
                #pragma unroll
                for (int k = 0; k < 10; ++k) acc += s_coef[g][1+k] * s_SJ[k*48 + t];
                s_J[g][t] = acc;
            }
            if (t < 16) {
                float* Jg = s_J[g];
                float res[12];
                #pragma unroll
                for (int p = 0; p < 3; ++p) {
                    res[p*4+0] = s_R0[g][p*3+0];
                    res[p*4+1] = s_R0[g][p*3+1];
                    res[p*4+2] = s_R0[g][p*3+2];
                    res[p*4+3] = Jg[p];
                }
                if (t >= 1) {
                    int start = ((t-1)/3)*3 + 1;
                    int d = t - start;
                    for (int s = 0; s < 3; ++s) {
                        if (s <= d) {
                            int a  = start + s;
                            int pa = (s == 0) ? 0 : (a - 1);
                            const float* cr = &s_coef[g][11 + (a-1)*9];
                            float Ra[9];
                            #pragma unroll
                            for (int i = 0; i < 9; ++i)
                                Ra[i] = cr[i] + ((i % 4 == 0) ? 1.f : 0.f);
                            float ax = Jg[a*3+0] - Jg[pa*3+0];
                            float ay = Jg[a*3+1] - Jg[pa*3+1];
                            float az = Jg[a*3+2] - Jg[pa*3+2];
                            float nr[12];
                            #pragma unroll
                            for (int p = 0; p < 3; ++p) {
                                float r0 = res[p*4+0], r1 = res[p*4+1], r2 = res[p*4+2];
                                #pragma unroll
                                for (int q = 0; q < 3; ++q)
                                    nr[p*4+q] = r0*Ra[q] + r1*Ra[3+q] + r2*Ra[6+q];
                                nr[p*4+3] = r0*ax + r1*ay + r2*az + res[p*4+3];
                            }
                            #pragma unroll
                            for (int q = 0; q < 12; ++q) res[q] = nr[q];
                        }
                    }
                }
                float jx = Jg[t*3+0], jy = Jg[t*3+1], jz = Jg[t*3+2];
                #pragma unroll
                for (int p = 0; p < 3; ++p) {
                    float r0 = res[p*4+0], r1 = res[p*4+1], r2 = res[p*4+2];
                    float ib = r0*jx + r1*jy + r2*jz;
                    s_A[g][t*12 + p*4+0] = r0;
                    s_A[g][t*12 + p*4+1] = r1;
                    s_A[g][t*12 + p*4+2] = r2;
                    s_A[g][t*12 + p*4+3] = res[p*4+3] - ib;
                }
            }
        }
    }
    __syncthreads();

    float acc[GC][3];
    #pragma unroll
    for (int g = 0; g < GC; ++g) { acc[g][0]=0.f; acc[g][1]=0.f; acc[g][2]=0.f; }
    for (int k = 0; k < NKQ; k += 8) {
        float nxt0[8], nxt1[8], nxt2[8];
        if (k + 8 < NKQ) {
            #pragma unroll
            for (int kk = 0; kk < 8; ++kk) {
                const float* gq = Gq + ((size_t)(k+8+kk)*256 + tid)*3;
                nxt0[kk] = gq[0]; nxt1[kk] = gq[1]; nxt2[kk] = gq[2];
            }
        }
        #pragma unroll
        for (int g = 0; g < GC; ++g) {
            float4 cA = *(const float4*)&s_coef[g][k];
            float4 cB = *(const float4*)&s_coef[g][k+4];
            float cf[8] = {cA.x,cA.y,cA.z,cA.w, cB.x,cB.y,cB.z,cB.w};
            #pragma unroll
            for (int kk = 0; kk < 8; ++kk) {
                acc[g][0] += cf[kk]*cur0[kk];
                acc[g][1] += cf[kk]*cur1[kk];
                acc[g][2] += cf[kk]*cur2[kk];
            }
        }
        if (k + 8 < NKQ) {
            #pragma unroll
            for (int kk = 0; kk < 8; ++kk) {
                cur0[kk] = nxt0[kk]; cur1[kk] = nxt1[kk]; cur2[kk] = nxt2[kk];
            }
        }
    }

    {
        const int J = tid >> 4, j = tid & 15;
        #pragma unroll
        for (int g = 0; g < GC; ++g) {
            const float* Aj = &s_A[g][j*12];
            float wj = s_WJ[J*16 + j];
            float v0 = Aj[0]*acc[g][0] + Aj[1]*acc[g][1] + Aj[2]*acc[g][2]  + Aj[3]*wj;
            float v1 = Aj[4]*acc[g][0] + Aj[5]*acc[g][1] + Aj[6]*acc[g][2]  + Aj[7]*wj;
            float v2 = Aj[8]*acc[g][0] + Aj[9]*acc[g][1] + Aj[10]*acc[g][2] + Aj[11]*wj;
            #pragma unroll
            for (int off = 1; off < 16; off <<= 1) {
                v0 += __shfl_xor(v0, off, 64);
                v1 += __shfl_xor(v1, off, 64);
                v2 += __shfl_xor(v2, off, 64);
            }
            int b = b0 + g;
            if (j == 0 && b < Btot) {
                float* ob = out + (size_t)b*63 + J*3;
                ob[0] = v0; ob[1] = v1; ob[2] = v2;
            }
        }
    }

    if (tid < GC*30) {
        int g = tid / 30, rem = tid % 30, sl = rem / 15, r = rem % 15;
        int k0 = sl*73, k1 = (k0+73 < NK) ? k0+73 : NK;
        float a = 0.f;
        for (int k = k0; k < k1; ++k) a += s_coef[g][k] * Dfing[k*15 + r];
        s_fred[g][r][sl] = a;
    }
    __syncthreads();
    if (tid < GC*15) {
        int g = tid / 15, r = tid % 15;
        s_vpf[g][r] = s_fred[g][r][0] + s_fred[g][r][1];
    }
    __syncthreads();
    if (tid < GC*15) {
        int g = tid / 15, r = tid % 15, f = r / 3, p = r % 3;
        int b = b0 + g;
        if (b < Btot) {
            const float* Ag = s_A[g];
            float vx = s_vpf[g][f*3+0], vy = s_vpf[g][f*3+1], vz = s_vpf[g][f*3+2];
            float val = 0.f;
            #pragma unroll
            for (int j = 0; j < 16; ++j) {
                float wj = Wfing[f*16 + j];
                val += wj * (Ag[j*12 + p*4 + 0]*vx +
                             Ag[j*12 + p*4 + 1]*vy +
                             Ag[j*12 + p*4 + 2]*vz +
                             Ag[j*12 + p*4 + 3]);
            }
            out[(size_t)b*63 + (16+f)*3 + p] = val;
        }
    }
}

extern "C" void kernel_launch(void* const* d_in, const int* in_sizes, int n_in,
                              void* d_out, int out_size, void* d_ws, size_t ws_size,
                              hipStream_t stream) {
    const float* beta       = (const float*)d_in[0];
    const float* theta      = (const float*)d_in[1];
    const float* v_template = (const float*)d_in[2];
    const float* shapedirs  = (const float*)d_in[3];
    const float* posedirs   = (const float*)d_in[4];
    const float* J_reg      = (const float*)d_in[5];
    const float* weights    = (const float*)d_in[6];
    const float* hands_mean = (const float*)d_in[7];
    const float* hands_comp = (const float*)d_in[8];
    float* out = (float*)d_out;

    const int B = in_sizes[0] / 10;
    const int npb = (B + 7) / 8;

    // workspace layout (floats)
    float* W = (float*)d_ws;
    float* SJ    = W;                          // 480
    float* JT    = W + 480;                    // 48
    float* WJ    = W + 528;                    // 256
    float* Dfing = W + 784;                    // 2190
    float* Wfing = W + 2974;                   // 80
    float* Gq    = W + 3072;                   // 152*256*3 = 116736
    float* Gqp   = W + 119808;                 // 8*146*768 = 897024
    float* coefG = W + 1016832;                // B*152
    float* R0G   = coefG + (size_t)B*152;      // B*9

    k_fold<<<1365 + npb, 256, 0, stream>>>(v_template, shapedirs, posedirs, J_reg,
                                           weights, beta, theta, hands_mean, hands_comp,
                                           SJ, JT, WJ, Gqp, coefG, R0G, Dfing, Wfing,
                                           B, npb);
    k_red<<<NKQ, 256, 0, stream>>>(Gqp, Gq);
    kC<<<(B + GC - 1)/GC, 256, 0, stream>>>(SJ, JT, WJ, Gq, coefG, R0G,
                                            Dfing, Wfing, out, B);
}

// Round 16
// 121.015 us; speedup vs baseline: 1.0217x; 1.0217x over previous
//
#include <hip/hip_runtime.h>

#define NV  778
#define NK  146    // coef: 1 (template) + 10 (beta) + 135 (pose_feature)
#define NKQ 152    // Gq rows padded to multiple of 8 (rows 146..151 zero)
#define GC  8      // batches per kC block (512 blocks = 2/CU)
#define VCH 98     // v-chunk per Gq fold block (8 chunks cover 778)
#define NCH 8      // chunk count

// Finger vertex ids
#define FV0 734
#define FV1 333
#define FV2 443
#define FV3 555
#define FV4 678

__device__ __forceinline__ const float* d_row(int k,
                                              const float* vt,
                                              const float* sd,
                                              const float* pd) {
    return (k == 0) ? vt : (k <= 10 ? sd + (size_t)(k-1)*(NV*3)
                                    : pd + (size_t)(k-11)*(NV*3));
}

__device__ __forceinline__ unsigned short f2bf(float x) {
    unsigned u = __float_as_uint(x);
    unsigned r = (u + 0x7fff + ((u >> 16) & 1)) >> 16;   // RNE
    return (unsigned short)r;
}
__device__ __forceinline__ float bf2f(unsigned short u) {
    return __uint_as_float((unsigned)u << 16);
}

// ---------------------------------------------------------------------------
// k_fold (reverted to R14 — best measured): roles by blockIdx:
//   [0,1168)         Gq partials -> Gqp (plain stores, no atomics)
//   [1168,1300)      SJ[480]/JT[48]
//   [1300,1364)      WJ[256]
//   [1364,1364+npb)  pose PCA + Rodrigues -> coefG/R0G
//   1364+npb         Dfing/Wfing gathers
// ---------------------------------------------------------------------------
__launch_bounds__(256)
__global__ void k_fold(const float* __restrict__ vt,
                       const float* __restrict__ sd,
                       const float* __restrict__ pd,
                       const float* __restrict__ jreg,
                       const float* __restrict__ wts,
                       const float* __restrict__ beta,
                       const float* __restrict__ theta,
                       const float* __restrict__ hm,
                       const float* __restrict__ hc,
                       float* __restrict__ SJ, float* __restrict__ JT,
                       float* __restrict__ WJ, float* __restrict__ Gqp,
                       float* __restrict__ coefG, float* __restrict__ R0G,
                       float* __restrict__ Dfing, float* __restrict__ Wfing,
                       int Btot, int npb)
{
    const int o = blockIdx.x;
    const int tid = threadIdx.x;

    __shared__ float p_hc[2025];
    __shared__ float p_th[8][48];
    __shared__ float p_pose[8][45];
    __shared__ float l_j[VCH*16];
    __shared__ float l_w[VCH*16];
    __shared__ float l_d[VCH*3];

    if (o < 1168) {
        const int k = o >> 3, chunk = o & 7;
        const float* Drow = d_row(k, vt, sd, pd);
        const int v0 = chunk * VCH;
        const int v1 = (v0 + VCH < NV) ? (v0 + VCH) : NV;
        const int n = v1 - v0;
        for (int i = tid; i < n*16; i += 256) l_j[i] = jreg[v0*16 + i];
        for (int i = tid; i < n*16; i += 256) l_w[i] = wts[v0*16 + i];
        for (int i = tid; i < n*3;  i += 256) l_d[i] = Drow[v0*3 + i];
        __syncthreads();
        const int J = tid >> 4, j = tid & 15;
        float a0 = 0.f, a1 = 0.f, a2 = 0.f;
        #pragma unroll 7
        for (int v = 0; v < n; ++v) {
            float pv = l_j[v*16 + J] * l_w[v*16 + j];
            a0 += l_d[v*3+0] * pv;
            a1 += l_d[v*3+1] * pv;
            a2 += l_d[v*3+2] * pv;
        }
        float* gp = Gqp + (((size_t)chunk*NK + k)*256 + tid)*3;
        gp[0] = a0; gp[1] = a1; gp[2] = a2;
    } else if (o < 1300) {
        const int idx = (o - 1168)*4 + (tid >> 6);   // 0..527
        const int t = tid & 63;
        const float* src; int jc;
        if (idx < 480) { int k = idx / 48; jc = idx % 48; src = sd + (size_t)k*(NV*3); }
        else           { jc = idx - 480;              src = vt; }
        int j = jc / 3, c = jc % 3;
        float acc = 0.f;
        for (int v = t; v < NV; v += 64)
            acc += src[3*v + c] * jreg[v*16 + j];
        for (int off = 32; off; off >>= 1) acc += __shfl_down(acc, off, 64);
        if (t == 0) { if (idx < 480) SJ[idx] = acc; else JT[jc] = acc; }
    } else if (o < 1364) {
        const int cidx = (o - 1300)*4 + (tid >> 6);  // 0..255
        const int t = tid & 63;
        const int J = cidx >> 4, j = cidx & 15;
        float acc = 0.f;
        for (int v = t; v < NV; v += 64)
            acc += jreg[v*16 + J] * wts[v*16 + j];
        for (int off = 32; off; off >>= 1) acc += __shfl_down(acc, off, 64);
        if (t == 0) WJ[cidx] = acc;
    } else if (o < 1364 + npb) {
        const int b0 = (o - 1364) * 8;
        for (int i = tid; i < 2025; i += 256) p_hc[i] = hc[i];
        for (int i = tid; i < 8*48; i += 256) {
            int g = i / 48, t = i % 48, b = b0 + g;
            p_th[g][t] = (b < Btot) ? theta[(size_t)b*48 + t] : 0.f;
        }
        __syncthreads();
        for (int i = tid; i < 8*45; i += 256) {
            int g = i / 45, t = i % 45;
            float acc = hm[t];
            #pragma unroll 9
            for (int k = 0; k < 45; ++k) acc += p_th[g][3+k] * p_hc[k*45 + t];
            p_pose[g][t] = acc;
        }
        __syncthreads();
        if (tid < 128) {
            int g = tid >> 4, jt = tid & 15;
            int b = b0 + g;
            if (b < Btot) {
                float rx, ry, rz;
                if (jt == 0) { rx = p_th[g][0]; ry = p_th[g][1]; rz = p_th[g][2]; }
                else { rx = p_pose[g][3*(jt-1)+0]; ry = p_pose[g][3*(jt-1)+1]; rz = p_pose[g][3*(jt-1)+2]; }
                float ex = rx + 1e-8f, ey = ry + 1e-8f, ez = rz + 1e-8f;
                float angle = sqrtf(ex*ex + ey*ey + ez*ez);
                float inv = 1.f / angle;
                float x = rx*inv, y = ry*inv, z = rz*inv;
                float s  = sinf(angle);
                float c1 = 1.f - cosf(angle);
                float R[9];
                R[0] = 1.f + c1*(-(z*z + y*y));
                R[1] = -s*z + c1*(x*y);
                R[2] =  s*y + c1*(x*z);
                R[3] =  s*z + c1*(x*y);
                R[4] = 1.f + c1*(-(x*x + z*z));
                R[5] = -s*x + c1*(y*z);
                R[6] = -s*y + c1*(x*z);
                R[7] =  s*x + c1*(y*z);
                R[8] = 1.f + c1*(-(x*x + y*y));
                float* cg = coefG + (size_t)b*152;
                if (jt == 0) {
                    #pragma unroll
                    for (int i = 0; i < 9; ++i) R0G[(size_t)b*9 + i] = R[i];
                    cg[0] = 1.f;
                    #pragma unroll
                    for (int k = 0; k < 10; ++k) cg[1+k] = beta[(size_t)b*10 + k];
                    #pragma unroll
                    for (int k = 146; k < 152; ++k) cg[k] = 0.f;
                } else {
                    #pragma unroll
                    for (int i = 0; i < 9; ++i)
                        cg[11 + (jt-1)*9 + i] = R[i] - ((i % 4 == 0) ? 1.f : 0.f);
                }
            }
        }
    } else {
        const int fv[5] = {FV0, FV1, FV2, FV3, FV4};
        for (int e = tid; e < NK*15; e += 256) {
            int k = e / 15, r = e % 15, f = r / 3, q = r % 3;
            Dfing[e] = d_row(k, vt, sd, pd)[3*fv[f] + q];
        }
        if (tid < 80) {
            int f = tid >> 4, j = tid & 15;
            Wfing[tid] = wts[fv[f]*16 + j];
        }
    }
}

// ---------------------------------------------------------------------------
// k_red: reduce partials in fp32, pack to bf16 ushort4 (q0,q1,q2,0).
// ---------------------------------------------------------------------------
__launch_bounds__(256)
__global__ void k_red(const float* __restrict__ Gqp, ushort4* __restrict__ Gqb)
{
    const int k = blockIdx.x;      // 0..NKQ-1
    const int c = threadIdx.x;     // 0..255
    float a0 = 0.f, a1 = 0.f, a2 = 0.f;
    if (k < NK) {
        #pragma unroll
        for (int ch = 0; ch < NCH; ++ch) {
            const float* gp = Gqp + (((size_t)ch*NK + k)*256 + c)*3;
            a0 += gp[0]; a1 += gp[1]; a2 += gp[2];
        }
    }
    ushort4 u;
    u.x = f2bf(a0); u.y = f2bf(a1); u.z = f2bf(a2); u.w = 0;
    Gqb[(size_t)k*256 + c] = u;
}

// ---------------------------------------------------------------------------
// kC: GC=8, 512 blocks; phase 2 reads bf16-packed Gq (8 B per (k,c)).
// ---------------------------------------------------------------------------
__launch_bounds__(256)
__global__ void kC(const float* __restrict__ SJ,
                   const float* __restrict__ JT,
                   const float* __restrict__ WJ,
                   const ushort4* __restrict__ Gqb,
                   const float* __restrict__ coefG,
                   const float* __restrict__ R0G,
                   const float* __restrict__ Dfing,
                   const float* __restrict__ Wfing,
                   float* __restrict__ out,
                   int Btot)
{
    const int tid = threadIdx.x;
    const int w = tid >> 6, t = tid & 63;
    const int b0 = blockIdx.x * GC;

    __shared__ float s_SJ[480];
    __shared__ float s_JT[48];
    __shared__ float s_WJ[256];
    __shared__ __align__(16) float s_coef[GC][152];
    __shared__ float s_R0[GC][9];
    __shared__ float s_A[GC][192];
    __shared__ float s_J[GC][48];
    __shared__ float s_vpf[GC][16];
    __shared__ float s_fred[GC][15][2];

    // prefetch group 0 (packed)
    ushort4 curU[8];
    #pragma unroll
    for (int kk = 0; kk < 8; ++kk)
        curU[kk] = Gqb[(size_t)kk*256 + tid];

    for (int i = tid; i < 480; i += 256) s_SJ[i] = SJ[i];
    if (tid < 48) s_JT[tid] = JT[tid];
    s_WJ[tid] = WJ[tid];
    for (int i = tid; i < GC*152; i += 256) {
        int g = i / 152, k = i % 152, b = b0 + g;
        s_coef[g][k] = (b < Btot) ? coefG[(size_t)b*152 + k] : 0.f;
    }
    if (tid < GC*9) {
        int g = tid / 9, i = tid % 9, b = b0 + g;
        s_R0[g][i] = (b < Btot) ? R0G[(size_t)b*9 + i] : 0.f;
    }
    __syncthreads();

    #pragma unroll
    for (int pp = 0; pp < 2; ++pp) {
        const int g = pp*4 + w;
        const int b = b0 + g;
        if (b < Btot) {
            if (t < 48) {
                float acc = s_JT[t];
                #pragma unroll
                for (int k = 0; k < 10; ++k) acc += s_coef[g][1+k] * s_SJ[k*48 + t];
                s_J[g][t] = acc;
            }
            if (t < 16) {
                float* Jg = s_J[g];
                float res[12];
                #pragma unroll
                for (int p = 0; p < 3; ++p) {
                    res[p*4+0] = s_R0[g][p*3+0];
                    res[p*4+1] = s_R0[g][p*3+1];
                    res[p*4+2] = s_R0[g][p*3+2];
                    res[p*4+3] = Jg[p];
                }
                if (t >= 1) {
                    int start = ((t-1)/3)*3 + 1;
                    int d = t - start;
                    for (int s = 0; s < 3; ++s) {
                        if (s <= d) {
                            int a  = start + s;
                            int pa = (s == 0) ? 0 : (a - 1);
                            const float* cr = &s_coef[g][11 + (a-1)*9];
                            float Ra[9];
                            #pragma unroll
                            for (int i = 0; i < 9; ++i)
                                Ra[i] = cr[i] + ((i % 4 == 0) ? 1.f : 0.f);
                            float ax = Jg[a*3+0] - Jg[pa*3+0];
                            float ay = Jg[a*3+1] - Jg[pa*3+1];
                            float az = Jg[a*3+2] - Jg[pa*3+2];
                            float nr[12];
                            #pragma unroll
                            for (int p = 0; p < 3; ++p) {
                                float r0 = res[p*4+0], r1 = res[p*4+1], r2 = res[p*4+2];
                                #pragma unroll
                                for (int q = 0; q < 3; ++q)
                                    nr[p*4+q] = r0*Ra[q] + r1*Ra[3+q] + r2*Ra[6+q];
                                nr[p*4+3] = r0*ax + r1*ay + r2*az + res[p*4+3];
                            }
                            #pragma unroll
                            for (int q = 0; q < 12; ++q) res[q] = nr[q];
                        }
                    }
                }
                float jx = Jg[t*3+0], jy = Jg[t*3+1], jz = Jg[t*3+2];
                #pragma unroll
                for (int p = 0; p < 3; ++p) {
                    float r0 = res[p*4+0], r1 = res[p*4+1], r2 = res[p*4+2];
                    float ib = r0*jx + r1*jy + r2*jz;
                    s_A[g][t*12 + p*4+0] = r0;
                    s_A[g][t*12 + p*4+1] = r1;
                    s_A[g][t*12 + p*4+2] = r2;
                    s_A[g][t*12 + p*4+3] = res[p*4+3] - ib;
                }
            }
        }
    }
    __syncthreads();

    float acc[GC][3];
    #pragma unroll
    for (int g = 0; g < GC; ++g) { acc[g][0]=0.f; acc[g][1]=0.f; acc[g][2]=0.f; }
    for (int k = 0; k < NKQ; k += 8) {
        ushort4 nxtU[8];
        if (k + 8 < NKQ) {
            #pragma unroll
            for (int kk = 0; kk < 8; ++kk)
                nxtU[kk] = Gqb[(size_t)(k+8+kk)*256 + tid];
        }
        float g0[8], g1[8], g2[8];
        #pragma unroll
        for (int kk = 0; kk < 8; ++kk) {
            g0[kk] = bf2f(curU[kk].x);
            g1[kk] = bf2f(curU[kk].y);
            g2[kk] = bf2f(curU[kk].z);
        }
        #pragma unroll
        for (int g = 0; g < GC; ++g) {
            float4 cA = *(const float4*)&s_coef[g][k];
            float4 cB = *(const float4*)&s_coef[g][k+4];
            float cf[8] = {cA.x,cA.y,cA.z,cA.w, cB.x,cB.y,cB.z,cB.w};
            #pragma unroll
            for (int kk = 0; kk < 8; ++kk) {
                acc[g][0] += cf[kk]*g0[kk];
                acc[g][1] += cf[kk]*g1[kk];
                acc[g][2] += cf[kk]*g2[kk];
            }
        }
        if (k + 8 < NKQ) {
            #pragma unroll
            for (int kk = 0; kk < 8; ++kk) curU[kk] = nxtU[kk];
        }
    }

    {
        const int J = tid >> 4, j = tid & 15;
        #pragma unroll
        for (int g = 0; g < GC; ++g) {
            const float* Aj = &s_A[g][j*12];
            float wj = s_WJ[J*16 + j];
            float v0 = Aj[0]*acc[g][0] + Aj[1]*acc[g][1] + Aj[2]*acc[g][2]  + Aj[3]*wj;
            float v1 = Aj[4]*acc[g][0] + Aj[5]*acc[g][1] + Aj[6]*acc[g][2]  + Aj[7]*wj;
            float v2 = Aj[8]*acc[g][0] + Aj[9]*acc[g][1] + Aj[10]*acc[g][2] + Aj[11]*wj;
            #pragma unroll
            for (int off = 1; off < 16; off <<= 1) {
                v0 += __shfl_xor(v0, off, 64);
                v1 += __shfl_xor(v1, off, 64);
                v2 += __shfl_xor(v2, off, 64);
            }
            int b = b0 + g;
            if (j == 0 && b < Btot) {
                float* ob = out + (size_t)b*63 + J*3;
                ob[0] = v0; ob[1] = v1; ob[2] = v2;
            }
        }
    }

    if (tid < GC*30) {
        int g = tid / 30, rem = tid % 30, sl = rem / 15, r = rem % 15;
        int k0 = sl*73, k1 = (k0+73 < NK) ? k0+73 : NK;
        float a = 0.f;
        for (int k = k0; k < k1; ++k) a += s_coef[g][k] * Dfing[k*15 + r];
        s_fred[g][r][sl] = a;
    }
    __syncthreads();
    if (tid < GC*15) {
        int g = tid / 15, r = tid % 15;
        s_vpf[g][r] = s_fred[g][r][0] + s_fred[g][r][1];
    }
    __syncthreads();
    if (tid < GC*15) {
        int g = tid / 15, r = tid % 15, f = r / 3, p = r % 3;
        int b = b0 + g;
        if (b < Btot) {
            const float* Ag = s_A[g];
            float vx = s_vpf[g][f*3+0], vy = s_vpf[g][f*3+1], vz = s_vpf[g][f*3+2];
            float val = 0.f;
            #pragma unroll
            for (int j = 0; j < 16; ++j) {
                float wj = Wfing[f*16 + j];
                val += wj * (Ag[j*12 + p*4 + 0]*vx +
                             Ag[j*12 + p*4 + 1]*vy +
                             Ag[j*12 + p*4 + 2]*vz +
                             Ag[j*12 + p*4 + 3]);
            }
            out[(size_t)b*63 + (16+f)*3 + p] = val;
        }
    }
}

extern "C" void kernel_launch(void* const* d_in, const int* in_sizes, int n_in,
                              void* d_out, int out_size, void* d_ws, size_t ws_size,
                              hipStream_t stream) {
    const float* beta       = (const float*)d_in[0];
    const float* theta      = (const float*)d_in[1];
    const float* v_template = (const float*)d_in[2];
    const float* shapedirs  = (const float*)d_in[3];
    const float* posedirs   = (const float*)d_in[4];
    const float* J_reg      = (const float*)d_in[5];
    const float* weights    = (const float*)d_in[6];
    const float* hands_mean = (const float*)d_in[7];
    const float* hands_comp = (const float*)d_in[8];
    float* out = (float*)d_out;

    const int B = in_sizes[0] / 10;
    const int npb = (B + 7) / 8;

    // workspace layout (floats)
    float* W = (float*)d_ws;
    float* SJ    = W;                          // 480
    float* JT    = W + 480;                    // 48
    float* WJ    = W + 528;                    // 256
    float* Dfing = W + 784;                    // 2190
    float* Wfing = W + 2974;                   // 80
    ushort4* Gqb = (ushort4*)(W + 3072);       // 152*256*8 B = 77824 floats
    float* Gqp   = W + 119808;                 // 8*146*768 = 897024
    float* coefG = W + 1016832;                // B*152
    float* R0G   = coefG + (size_t)B*152;      // B*9

    k_fold<<<1365 + npb, 256, 0, stream>>>(v_template, shapedirs, posedirs, J_reg,
                                           weights, beta, theta, hands_mean, hands_comp,
                                           SJ, JT, WJ, Gqp, coefG, R0G, Dfing, Wfing,
                                           B, npb);
    k_red<<<NKQ, 256, 0, stream>>>(Gqp, Gqb);
    kC<<<(B + GC - 1)/GC, 256, 0, stream>>>(SJ, JT, WJ, Gqb, coefG, R0G,
                                            Dfing, Wfing, out, B);
}